// Round 1
// baseline (1581.856 us; speedup 1.0000x reference)
//
#include <hip/hip_runtime.h>

#define N_NODES 50000
#define N_EDGES 600000
#define DIM     128

// ---------------------------------------------------------------------------
// Degree computation: one thread per edge, atomicAdd into deg[dst].
// ---------------------------------------------------------------------------
__global__ void deg_kernel(const int* __restrict__ dst, float* __restrict__ deg) {
    int e = blockIdx.x * blockDim.x + threadIdx.x;
    if (e < N_EDGES) atomicAdd(&deg[dst[e]], 1.0f);
}

__global__ void invdeg_kernel(float* __restrict__ deg) {
    int n = blockIdx.x * blockDim.x + threadIdx.x;
    if (n < N_NODES) deg[n] = 1.0f / fmaxf(deg[n], 1.0f);
}

// ---------------------------------------------------------------------------
// Scatter-add aggregation: 2 edges per 256-thread block, 128 threads/edge.
// Thread t: edge = blockIdx.x*2 + (t>>7), dim = t&127.
// Reads h[src] coalesced per-dim, atomicAdd to agg[dst] coalesced per-dim.
// ---------------------------------------------------------------------------
__global__ __launch_bounds__(256) void scatter_kernel(
    const int* __restrict__ src, const int* __restrict__ dst,
    const float* __restrict__ h, float* __restrict__ agg) {
    int t = threadIdx.x;
    int e = blockIdx.x * 2 + (t >> 7);
    int d = t & 127;
    int s = src[e];
    int r = dst[e];
    float v = h[(size_t)s * DIM + d];
    atomicAdd(&agg[(size_t)r * DIM + d], v);
}

// ---------------------------------------------------------------------------
// Fused SAGEConv GEMM: out[n][j] = relu( (agg[n]*invdeg[n]) @ Wl + h[n] @ Wr + b )
// 8 rows per 256-thread block. Rows staged in LDS (broadcast reads),
// weights streamed from L2 (coalesced 64-lane reads), 4 outputs/thread.
// ---------------------------------------------------------------------------
__global__ __launch_bounds__(256) void sage_gemm_kernel(
    const float* __restrict__ agg, const float* __restrict__ hin,
    const float* __restrict__ invdeg,
    const float* __restrict__ Wl, const float* __restrict__ Wr,
    const float* __restrict__ bias, float* __restrict__ hout) {
    __shared__ float s_a[8][DIM];
    __shared__ float s_h[8][DIM];
    int t = threadIdx.x;
    int row0 = blockIdx.x * 8;

    // Stage 8 rows of (agg * invdeg) and h into LDS. 2048 elems x2, 256 thr.
    for (int i = t; i < 8 * DIM; i += 256) {
        int r = i >> 7;      // 0..7
        int d = i & 127;
        float id = invdeg[row0 + r];
        s_a[r][d] = agg[(size_t)(row0 + r) * DIM + d] * id;
        s_h[r][d] = hin[(size_t)(row0 + r) * DIM + d];
    }
    __syncthreads();

    int col = t & 127;
    int rg  = t >> 7;  // 0 or 1; thread handles rows rg, rg+2, rg+4, rg+6
    float acc0 = 0.f, acc1 = 0.f, acc2 = 0.f, acc3 = 0.f;

    #pragma unroll 8
    for (int k = 0; k < DIM; k++) {
        float wl = Wl[k * DIM + col];
        float wr = Wr[k * DIM + col];
        acc0 += s_a[rg + 0][k] * wl + s_h[rg + 0][k] * wr;
        acc1 += s_a[rg + 2][k] * wl + s_h[rg + 2][k] * wr;
        acc2 += s_a[rg + 4][k] * wl + s_h[rg + 4][k] * wr;
        acc3 += s_a[rg + 6][k] * wl + s_h[rg + 6][k] * wr;
    }

    float bb = bias[col];
    hout[(size_t)(row0 + rg + 0) * DIM + col] = fmaxf(acc0 + bb, 0.f);
    hout[(size_t)(row0 + rg + 2) * DIM + col] = fmaxf(acc1 + bb, 0.f);
    hout[(size_t)(row0 + rg + 4) * DIM + col] = fmaxf(acc2 + bb, 0.f);
    hout[(size_t)(row0 + rg + 6) * DIM + col] = fmaxf(acc3 + bb, 0.f);
}

// ---------------------------------------------------------------------------
// Launch
// ---------------------------------------------------------------------------
extern "C" void kernel_launch(void* const* d_in, const int* in_sizes, int n_in,
                              void* d_out, int out_size, void* d_ws, size_t ws_size,
                              hipStream_t stream) {
    const float* x  = (const float*)d_in[0];
    const float* Wl = (const float*)d_in[1];
    const float* Wr = (const float*)d_in[2];
    const float* b  = (const float*)d_in[3];
    const int*   ei = (const int*)d_in[4];
    const int* src = ei;
    const int* dst = ei + N_EDGES;
    float* out = (float*)d_out;

    char* ws = (char*)d_ws;
    float* invdeg = (float*)ws;                              // 50000 floats
    float* agg    = (float*)(ws + 262144);                   // 25.6 MB
    float* hA     = (float*)(ws + 262144 + (size_t)N_NODES * DIM * 4);

    // Degree -> inv_deg (ws is poisoned every call; re-zero)
    hipMemsetAsync(invdeg, 0, N_NODES * sizeof(float), stream);
    deg_kernel<<<(N_EDGES + 255) / 256, 256, 0, stream>>>(dst, invdeg);
    invdeg_kernel<<<(N_NODES + 255) / 256, 256, 0, stream>>>(invdeg);

    const float* hin = x;
    float* houts[4] = { hA, out, hA, out };

    for (int l = 0; l < 4; l++) {
        hipMemsetAsync(agg, 0, (size_t)N_NODES * DIM * sizeof(float), stream);
        scatter_kernel<<<N_EDGES / 2, 256, 0, stream>>>(src, dst, hin, agg);
        sage_gemm_kernel<<<N_NODES / 8, 256, 0, stream>>>(
            agg, hin, invdeg,
            Wl + (size_t)l * DIM * DIM, Wr + (size_t)l * DIM * DIM, b + (size_t)l * DIM,
            houts[l]);
        hin = houts[l];
    }
}

// Round 2
// 732.988 us; speedup vs baseline: 2.1581x; 2.1581x over previous
//
#include <hip/hip_runtime.h>

#define N_NODES 50000
#define N_EDGES 600000
#define DIM     128

// ---------------------------------------------------------------------------
// CSR build step 1: int degree histogram over dst.
// ---------------------------------------------------------------------------
__global__ void deg_hist_kernel(const int* __restrict__ dst, int* __restrict__ deg) {
    int e = blockIdx.x * blockDim.x + threadIdx.x;
    if (e < N_EDGES) atomicAdd(&deg[dst[e]], 1);
}

// ---------------------------------------------------------------------------
// CSR build step 2: exclusive prefix sum of deg -> rowptr[0..N_NODES].
// Single block, 1024 threads, ~49 elements/thread + LDS Hillis-Steele scan.
// ---------------------------------------------------------------------------
__global__ __launch_bounds__(1024) void scan_kernel(const int* __restrict__ deg,
                                                    int* __restrict__ rowptr) {
    __shared__ int part[1024];
    const int CH = (N_NODES + 1023) / 1024;  // 49
    int t = threadIdx.x;
    int start = t * CH;
    int end   = min(start + CH, N_NODES);
    int s = 0;
    for (int i = start; i < end; i++) s += deg[i];
    part[t] = s;
    __syncthreads();
    for (int off = 1; off < 1024; off <<= 1) {
        int u = (t >= off) ? part[t - off] : 0;
        __syncthreads();
        part[t] += u;
        __syncthreads();
    }
    int base = part[t] - s;  // exclusive prefix
    int run = base;
    for (int i = start; i < end; i++) {
        rowptr[i] = run;
        run += deg[i];
    }
    if (t == 1023) rowptr[N_NODES] = run;  // == N_EDGES
}

// ---------------------------------------------------------------------------
// CSR build step 3: scatter edges into slots.
// ---------------------------------------------------------------------------
__global__ void fill_kernel(const int* __restrict__ src, const int* __restrict__ dst,
                            const int* __restrict__ rowptr, int* __restrict__ cursor,
                            int* __restrict__ csr_src) {
    int e = blockIdx.x * blockDim.x + threadIdx.x;
    if (e >= N_EDGES) return;
    int d = dst[e];
    int pos = rowptr[d] + atomicAdd(&cursor[d], 1);
    csr_src[pos] = src[e];
}

// ---------------------------------------------------------------------------
// Fused SAGEConv layer: per block, 8 nodes.
// Phase 1 (gather): 8 groups x 32 threads; group g aggregates node row0+g's
//   in-neighbors with float4 coalesced reads (L3-resident h), scales by
//   1/max(deg,1), stores to LDS; also stages the node's own h row.
// Phase 2 (GEMM): out[n][col] = relu(s_a[n]@Wl + s_h[n]@Wr + b), 4 rows/thread.
// ---------------------------------------------------------------------------
__global__ __launch_bounds__(256) void sage_layer_kernel(
    const int* __restrict__ rowptr, const int* __restrict__ csr_src,
    const float* __restrict__ hin,
    const float* __restrict__ Wl, const float* __restrict__ Wr,
    const float* __restrict__ bias, float* __restrict__ hout) {
    __shared__ float s_a[8][DIM];
    __shared__ float s_h[8][DIM];
    int t = threadIdx.x;
    int row0 = blockIdx.x * 8;

    // --- gather phase ---
    {
        int g  = t >> 5;          // node group 0..7
        int l4 = (t & 31) << 2;   // dim offset (float4)
        int node = row0 + g;
        int beg = rowptr[node], end = rowptr[node + 1];
        float ax = 0.f, ay = 0.f, az = 0.f, aw = 0.f;
        for (int i = beg; i < end; i++) {
            int s = csr_src[i];
            const float4 v = *(const float4*)&hin[(size_t)s * DIM + l4];
            ax += v.x; ay += v.y; az += v.z; aw += v.w;
        }
        float scale = 1.0f / fmaxf((float)(end - beg), 1.0f);
        float4 a4 = { ax * scale, ay * scale, az * scale, aw * scale };
        *(float4*)&s_a[g][l4] = a4;
        *(float4*)&s_h[g][l4] = *(const float4*)&hin[(size_t)node * DIM + l4];
    }
    __syncthreads();

    // --- GEMM phase ---
    int col = t & 127;
    int rg  = t >> 7;  // 0 or 1; rows rg, rg+2, rg+4, rg+6
    float acc0 = 0.f, acc1 = 0.f, acc2 = 0.f, acc3 = 0.f;

    #pragma unroll 8
    for (int k = 0; k < DIM; k++) {
        float wl = Wl[k * DIM + col];
        float wr = Wr[k * DIM + col];
        acc0 += s_a[rg + 0][k] * wl + s_h[rg + 0][k] * wr;
        acc1 += s_a[rg + 2][k] * wl + s_h[rg + 2][k] * wr;
        acc2 += s_a[rg + 4][k] * wl + s_h[rg + 4][k] * wr;
        acc3 += s_a[rg + 6][k] * wl + s_h[rg + 6][k] * wr;
    }

    float bb = bias[col];
    hout[(size_t)(row0 + rg + 0) * DIM + col] = fmaxf(acc0 + bb, 0.f);
    hout[(size_t)(row0 + rg + 2) * DIM + col] = fmaxf(acc1 + bb, 0.f);
    hout[(size_t)(row0 + rg + 4) * DIM + col] = fmaxf(acc2 + bb, 0.f);
    hout[(size_t)(row0 + rg + 6) * DIM + col] = fmaxf(acc3 + bb, 0.f);
}

// ---------------------------------------------------------------------------
// Launch
// ---------------------------------------------------------------------------
extern "C" void kernel_launch(void* const* d_in, const int* in_sizes, int n_in,
                              void* d_out, int out_size, void* d_ws, size_t ws_size,
                              hipStream_t stream) {
    const float* x  = (const float*)d_in[0];
    const float* Wl = (const float*)d_in[1];
    const float* Wr = (const float*)d_in[2];
    const float* b  = (const float*)d_in[3];
    const int*   ei = (const int*)d_in[4];
    const int* src = ei;
    const int* dst = ei + N_EDGES;
    float* out = (float*)d_out;

    char* ws = (char*)d_ws;
    int* deg     = (int*)ws;                         // 50000
    int* cursor  = deg + 50048;                      // 50000 (padded start)
    int* rowptr  = cursor + 50048;                   // 50001
    int* csr_src = rowptr + 50052;                   // 600000
    float* hA    = (float*)(csr_src + 600064);       // 25.6 MB

    // zero deg + cursor (rowptr fully overwritten by scan)
    hipMemsetAsync(deg, 0, (size_t)(50048 * 2) * sizeof(int), stream);

    deg_hist_kernel<<<(N_EDGES + 255) / 256, 256, 0, stream>>>(dst, deg);
    scan_kernel<<<1, 1024, 0, stream>>>(deg, rowptr);
    fill_kernel<<<(N_EDGES + 255) / 256, 256, 0, stream>>>(src, dst, rowptr, cursor, csr_src);

    const float* hin = x;
    float* houts[4] = { hA, out, hA, out };

    for (int l = 0; l < 4; l++) {
        sage_layer_kernel<<<N_NODES / 8, 256, 0, stream>>>(
            rowptr, csr_src, hin,
            Wl + (size_t)l * DIM * DIM, Wr + (size_t)l * DIM * DIM, b + (size_t)l * DIM,
            houts[l]);
        hin = houts[l];
    }
}